// Round 8
// baseline (166.264 us; speedup 1.0000x reference)
//
#include <hip/hip_runtime.h>

// Dtype contract: device buffers FP32 (reference dtypes); internal bf16 MFMA,
// fp32 accumulate. Tolerance is bf16-grade (2% of absmax).
// dur_us model: Σ(kernels) + ~65-68 us fixed harness resets — only the kernel
// sum is controllable.

#define BATCH 8
#define SEQ   2048
#define CIN   1024
#define HDIM  64
#define NROW  (BATCH * SEQ)      // 16384
#define NQT   (NROW / 16)        // 1024 q-tiles
#define UNITS 576                // per batch: sum over qt of (qt/16+1)

typedef __attribute__((ext_vector_type(8))) short bf16x8;
typedef __attribute__((ext_vector_type(4))) short u16x4;
typedef __attribute__((ext_vector_type(4))) float f32x4;

__device__ __forceinline__ unsigned short f2bf(float f) {
  unsigned int u = __builtin_bit_cast(unsigned int, f);
  u += 0x7fffu + ((u >> 16) & 1u);          // RNE
  return (unsigned short)(u >> 16);
}
__device__ __forceinline__ float bf2f(unsigned short h) {
  return __builtin_bit_cast(float, (unsigned int)h << 16);
}
__device__ __forceinline__ u16x4 pack4(f32x4 a) {
  u16x4 r;
  r[0] = (short)f2bf(a[0]); r[1] = (short)f2bf(a[1]);
  r[2] = (short)f2bf(a[2]); r[3] = (short)f2bf(a[3]);
  return r;
}

// ---------------- Kernel 0: W [C][HD] fp32 -> Wt [HD][C] bf16 (LDS tiles) ---
__global__ __launch_bounds__(256) void wtrans_k(const float* __restrict__ wq,
                                                const float* __restrict__ wk,
                                                const float* __restrict__ wv,
                                                unsigned short* __restrict__ wt) {
  __shared__ unsigned short lds[64][65];
  const int m  = blockIdx.x >> 4;
  const int c0 = (blockIdx.x & 15) * 64;
  const float* w = (m == 0) ? wq : (m == 1) ? wk : wv;
  const int nl = threadIdx.x & 63, gr = threadIdx.x >> 6;
#pragma unroll
  for (int i = 0; i < 16; ++i) {
    int cl = gr * 16 + i;
    lds[cl][nl] = f2bf(w[(size_t)(c0 + cl) * HDIM + nl]);
  }
  __syncthreads();
#pragma unroll
  for (int i = 0; i < 16; ++i) {
    int n = gr * 16 + i;
    wt[(size_t)m * 65536 + n * CIN + c0 + nl] = lds[nl][n];
  }
}

// ---------------- Kernel 1: QKV projection, LDS-staged GEMM -----------------
// (unchanged this round)
__global__ __launch_bounds__(512) void qkv_proj_k(const float* __restrict__ x,
                                                  const unsigned short* __restrict__ wt,
                                                  unsigned short* __restrict__ q,
                                                  unsigned short* __restrict__ k,
                                                  unsigned short* __restrict__ vt) {
  __shared__ __align__(16) unsigned char ldsb[28672];   // x @0, wt @4096
  const int tid  = threadIdx.x;
  const int lane = tid & 63;
  const int w    = tid >> 6;
  const int lr   = lane & 15, lg = lane >> 4;
  const int wm   = w & 1, wn = w >> 1;
  const int row0 = blockIdx.x * 32;

  const int trow  = tid >> 4;
  const int tcol4 = (tid & 15) * 4;
  const float* xg = x + (size_t)(row0 + trow) * CIN + tcol4;
  const int xoff  = trow * 128 + (((tcol4 >> 3) ^ (trow & 7)) << 4) + ((tcol4 & 4) << 1);

  const int wrow_ = tid >> 3;
  const int wg8   = tid & 7;
  const unsigned short* wg[3];
  int woff[3];
#pragma unroll
  for (int c = 0; c < 3; ++c) {
    int wrow = c * 64 + wrow_;
    wg[c]   = wt + (size_t)wrow * CIN + wg8 * 8;
    woff[c] = 4096 + wrow * 128 + ((wg8 ^ (wrow & 7)) << 4);
  }

  f32x4 acc[3];
#pragma unroll
  for (int i = 0; i < 3; ++i) acc[i] = (f32x4){0.f, 0.f, 0.f, 0.f};

  const int arow_off = (wm * 16 + lr) * 128;
  const int brow0    = wn * 48 + lr;

#pragma unroll 1
  for (int t = 0; t < 16; ++t) {
    const int k0 = t * 64;
    f32x4 xv = *(const f32x4*)(xg + k0);
    bf16x8 w0 = *(const bf16x8*)(wg[0] + k0);
    bf16x8 w1 = *(const bf16x8*)(wg[1] + k0);
    bf16x8 w2 = *(const bf16x8*)(wg[2] + k0);
    __syncthreads();
    *(u16x4*)(void*)(ldsb + xoff)    = pack4(xv);
    *(bf16x8*)(void*)(ldsb + woff[0]) = w0;
    *(bf16x8*)(void*)(ldsb + woff[1]) = w1;
    *(bf16x8*)(void*)(ldsb + woff[2]) = w2;
    __syncthreads();
#pragma unroll
    for (int kk = 0; kk < 2; ++kk) {
      const int swz = (((kk << 2) | lg) ^ (lr & 7)) << 4;
      bf16x8 af = *(const bf16x8*)(void*)(ldsb + arow_off + swz);
#pragma unroll
      for (int f = 0; f < 3; ++f) {
        bf16x8 bf_ = *(const bf16x8*)(void*)(ldsb + 4096 + (brow0 + f * 16) * 128 + swz);
        acc[f] = __builtin_amdgcn_mfma_f32_16x16x32_bf16(af, bf_, acc[f], 0, 0, 0);
      }
    }
  }

#pragma unroll
  for (int f = 0; f < 3; ++f) {
    const int gc  = wn * 48 + f * 16;
    const int mat = gc >> 6;
    const int hd  = (gc & 63) + lr;
#pragma unroll
    for (int j = 0; j < 4; ++j) {
      int grow = row0 + wm * 16 + lg * 4 + j;
      float v = acc[f][j];
      if (mat == 0) {
        q[(size_t)grow * HDIM + hd] = f2bf(v * 0.03125f);   // fold 1/sqrt(C)
      } else if (mat == 1) {
        k[(size_t)grow * HDIM + hd] = f2bf(v);
      } else {
        int b = grow >> 11, tp = grow & 2047;
        vt[((size_t)b * HDIM + hd) * SEQ + tp] = f2bf(v);
      }
    }
  }
}

// ---------------- Kernel 2: causal flash attention, balanced split-KV -------
// R7 lesson: the compiler sinks loads to their uses (VGPR stayed 64), leaving
// 1 VMEM in flight per wave -> 18 waves/CU x 128B/250cy = 5.7 TB/s = the
// measured 43 us. Fix: cluster ALL 16 K+V loads of a tile, then a hard
// sched_barrier(0) fence so they cannot sink. Compiler then emits its own
// counted vmcnt waits before each use (correct by construction).
__global__ __launch_bounds__(256, 3) void attn_k(const unsigned short* __restrict__ q,
                                                 const unsigned short* __restrict__ k,
                                                 const unsigned short* __restrict__ vt,
                                                 float* __restrict__ opart,
                                                 float* __restrict__ m_l) {
  __shared__ __align__(16) unsigned short plds[4][16][72];  // 144B row stride
  const int lane = threadIdx.x & 63;
  const int w    = threadIdx.x >> 6;
  const int lr = lane & 15, lg = lane >> 4;
  const int u    = blockIdx.x * 4 + w;      // 0 .. 8*UNITS-1
  const int b    = u / UNITS;
  const int unit = u - b * UNITS;
  // decode unit -> (a, qt, seg): band a covers units [8a(a+1), 8(a+1)(a+2))
  int a = 0;
#pragma unroll
  for (int i = 0; i < 7; ++i) if (8 * (a + 1) * (a + 2) <= unit) ++a;
  const int S    = a + 1;
  const int rem  = unit - 8 * a * S;
  const int qt   = 16 * a + rem / S;
  const int seg  = rem - (rem / S) * S;
  const int row0 = qt * 16;
  const int p    = b * UNITS + unit;        // partial slot
  unsigned short (*pw)[72] = plds[w];

  const unsigned short* qb_ = q  + (size_t)b * SEQ * HDIM;
  const unsigned short* kb_ = k  + (size_t)b * SEQ * HDIM;
  const unsigned short* vb_ = vt + (size_t)b * HDIM * SEQ;

  bf16x8 qf0 = *(const bf16x8*)(qb_ + (row0 + lr) * HDIM + lg * 8);
  bf16x8 qf1 = *(const bf16x8*)(qb_ + (row0 + lr) * HDIM + 32 + lg * 8);

  f32x4 o[4];
#pragma unroll
  for (int n = 0; n < 4; ++n) o[n] = (f32x4){0.f, 0.f, 0.f, 0.f};
  float m_run = -INFINITY, l_run = 0.f;
  const int   qrow = row0 + lr;
  const float LOG2E = 1.44269504f;
  const int nt = (qt >> 2) + 1;             // = ceil((row0+16)/64)
  const int lo = (nt * seg) / S;
  const int hi = (nt * (seg + 1)) / S;

  for (int t = lo; t < hi; ++t) {
    const int kv = t * 64;
    // ---- issue ALL 16 tile loads back-to-back (8 K + 8 V), then fence ----
    bf16x8 ka[8], vf[8];
#pragma unroll
    for (int f = 0; f < 4; ++f) {
      const unsigned short* kp = kb_ + (size_t)(kv + f * 16 + lr) * HDIM + lg * 8;
      ka[2 * f]     = *(const bf16x8*)(kp);
      ka[2 * f + 1] = *(const bf16x8*)(kp + 32);
    }
#pragma unroll
    for (int n = 0; n < 4; ++n) {
      const unsigned short* vp = vb_ + (size_t)(n * 16 + lr) * SEQ + kv + lg * 8;
      vf[n]     = *(const bf16x8*)(vp);        // kk = 0
      vf[4 + n] = *(const bf16x8*)(vp + 32);   // kk = 1
    }
    __builtin_amdgcn_sched_barrier(0);         // loads may NOT sink below here

    f32x4 sv[4];
#pragma unroll
    for (int f = 0; f < 4; ++f) {
      sv[f] = (f32x4){0.f, 0.f, 0.f, 0.f};
      sv[f] = __builtin_amdgcn_mfma_f32_16x16x32_bf16(ka[2 * f],     qf0, sv[f], 0, 0, 0);
      sv[f] = __builtin_amdgcn_mfma_f32_16x16x32_bf16(ka[2 * f + 1], qf1, sv[f], 0, 0, 0);
    }
    if (kv + 63 > row0) {                    // wave-uniform: tile touches diagonal
#pragma unroll
      for (int f = 0; f < 4; ++f)
#pragma unroll
        for (int j = 0; j < 4; ++j)
          if (kv + f * 16 + lg * 4 + j > qrow) sv[f][j] = -INFINITY;
    }
    float tm = -INFINITY;
#pragma unroll
    for (int f = 0; f < 4; ++f)
#pragma unroll
      for (int j = 0; j < 4; ++j) tm = fmaxf(tm, sv[f][j]);
    tm = fmaxf(tm, __shfl_xor(tm, 16, 64));
    tm = fmaxf(tm, __shfl_xor(tm, 32, 64));
    float m_new = fmaxf(m_run, tm);
    float alpha = (m_run == -INFINITY) ? 0.f : exp2f((m_run - m_new) * LOG2E);
    float mc    = (m_new == -INFINITY) ? 0.f : m_new * LOG2E;
    float ps = 0.f;
#pragma unroll
    for (int f = 0; f < 4; ++f) {
      float p0 = exp2f(sv[f][0] * LOG2E - mc);
      float p1 = exp2f(sv[f][1] * LOG2E - mc);
      float p2 = exp2f(sv[f][2] * LOG2E - mc);
      float p3 = exp2f(sv[f][3] * LOG2E - mc);
      ps += (p0 + p1) + (p2 + p3);
      unsigned int lo32 = (unsigned int)f2bf(p0) | ((unsigned int)f2bf(p1) << 16);
      unsigned int hi32 = (unsigned int)f2bf(p2) | ((unsigned int)f2bf(p3) << 16);
      uint2 pk; pk.x = lo32; pk.y = hi32;
      *(uint2*)(&pw[lr][f * 16 + lg * 4]) = pk;   // ds_write_b64
    }
    ps += __shfl_xor(ps, 16, 64);
    ps += __shfl_xor(ps, 32, 64);
    l_run = l_run * alpha + ps;
    m_run = m_new;
#pragma unroll
    for (int j = 0; j < 4; ++j) {
      float aj = __shfl(alpha, lg * 4 + j, 64);
      o[0][j] *= aj; o[1][j] *= aj; o[2][j] *= aj; o[3][j] *= aj;
    }
    // in-wave DS ordering: drain this wave's DS writes, then read P (no barriers)
    asm volatile("s_waitcnt lgkmcnt(0)" ::: "memory");
    __builtin_amdgcn_sched_barrier(0);
#pragma unroll
    for (int kk = 0; kk < 2; ++kk) {
      bf16x8 pf = *(const bf16x8*)(&pw[lr][kk * 32 + lg * 8]);
#pragma unroll
      for (int n = 0; n < 4; ++n)
        o[n] = __builtin_amdgcn_mfma_f32_16x16x32_bf16(pf, vf[kk * 4 + n], o[n], 0, 0, 0);
    }
  }

  if (lane < 16) {
    m_l[p * 32 + lane]      = m_run;
    m_l[p * 32 + 16 + lane] = l_run;
  }
#pragma unroll
  for (int j = 0; j < 4; ++j) {
    int r = lg * 4 + j;
#pragma unroll
    for (int n = 0; n < 4; ++n)
      opart[(size_t)p * 1024 + r * 64 + n * 16 + lr] = o[n][j];
  }
}

// ---------------- Kernel 3: combine variable-split partials -----------------
__global__ __launch_bounds__(256) void combine_k(const float* __restrict__ opart,
                                                 const float* __restrict__ m_l,
                                                 float* __restrict__ out) {
  const float LOG2E = 1.44269504f;
  int idx = blockIdx.x * 256 + threadIdx.x;
  int col = idx & 63;
  int row = idx >> 6;
  int b = row >> 11, t = row & 2047;
  int qt = t >> 4, r = t & 15;
  int a = qt >> 4;
  int S = a + 1;
  int pb = b * UNITS + 8 * a * S + (qt & 15) * S;   // base slot for this q-tile
  float M = -INFINITY;
  for (int s = 0; s < S; ++s) M = fmaxf(M, m_l[(pb + s) * 32 + r]);
  float l = 0.f, o = 0.f;
  for (int s = 0; s < S; ++s) {
    float ms = m_l[(pb + s) * 32 + r];
    float w  = exp2f((ms - M) * LOG2E);
    l += m_l[(pb + s) * 32 + 16 + r] * w;
    o += opart[(size_t)(pb + s) * 1024 + r * 64 + col] * w;
  }
  out[(size_t)row * HDIM + col] = o / l;
}

// ---------------- launch ----------------------------------------------------
extern "C" void kernel_launch(void* const* d_in, const int* in_sizes, int n_in,
                              void* d_out, int out_size, void* d_ws, size_t ws_size,
                              hipStream_t stream) {
  const float* x  = (const float*)d_in[0];
  const float* wq = (const float*)d_in[1];
  const float* wk = (const float*)d_in[2];
  const float* wv = (const float*)d_in[3];
  float* outp = (float*)d_out;

  const int NP = BATCH * UNITS;                         // 4608 partial slots
  float* m_l   = (float*)d_ws;                          // [NP][32]
  float* opart = m_l + (size_t)NP * 32;                 // [NP][16][64]
  unsigned short* qbuf = (unsigned short*)(opart + (size_t)NP * 1024);
  unsigned short* kbuf = qbuf + (size_t)NROW * HDIM;
  unsigned short* vbuf = kbuf + (size_t)NROW * HDIM;    // [B][64][T]
  unsigned short* wt   = vbuf + (size_t)NROW * HDIM;    // [3][64][1024]

  hipLaunchKernelGGL(wtrans_k, dim3(48), dim3(256), 0, stream, wq, wk, wv, wt);
  hipLaunchKernelGGL(qkv_proj_k, dim3(NROW / 32), dim3(512), 0, stream, x, wt, qbuf, kbuf, vbuf);
  hipLaunchKernelGGL(attn_k, dim3(NP / 4), dim3(256), 0, stream, qbuf, kbuf, vbuf, opart, m_l);
  hipLaunchKernelGGL(combine_k, dim3(NROW * HDIM / 256), dim3(256), 0, stream, opart, m_l, outp);
}

// Round 9
// 151.361 us; speedup vs baseline: 1.0985x; 1.0985x over previous
//
#include <hip/hip_runtime.h>

// Dtype contract: device buffers FP32 (reference dtypes); internal bf16 MFMA,
// fp32 accumulate. Tolerance is bf16-grade (2% of absmax).
// dur_us model: Σ(kernels) + ~65-68 us fixed harness resets.
// R8 lesson: hipcc sinks per-lane global loads to uses (VGPR stayed 60!) no
// matter what (early-issue, launch_bounds, sched_barrier). Multiple VMEM in
// flight at source level => bulk reg-staged LDS copy shared by many waves.

#define BATCH 8
#define SEQ   2048
#define CIN   1024
#define HDIM  64
#define NROW  (BATCH * SEQ)      // 16384
#define UPB   136                // units per batch: sum_{i=0..15} (i+1)
#define NPB   (BATCH * UPB)      // 1088 blocks / partial slots

typedef __attribute__((ext_vector_type(8))) short bf16x8;
typedef __attribute__((ext_vector_type(4))) short u16x4;
typedef __attribute__((ext_vector_type(4))) float f32x4;

__device__ __forceinline__ unsigned short f2bf(float f) {
  unsigned int u = __builtin_bit_cast(unsigned int, f);
  u += 0x7fffu + ((u >> 16) & 1u);          // RNE
  return (unsigned short)(u >> 16);
}
__device__ __forceinline__ float bf2f(unsigned short h) {
  return __builtin_bit_cast(float, (unsigned int)h << 16);
}
__device__ __forceinline__ u16x4 pack4(f32x4 a) {
  u16x4 r;
  r[0] = (short)f2bf(a[0]); r[1] = (short)f2bf(a[1]);
  r[2] = (short)f2bf(a[2]); r[3] = (short)f2bf(a[3]);
  return r;
}

// ---------------- Kernel 0: W [C][HD] fp32 -> Wt [HD][C] bf16 (LDS tiles) ---
__global__ __launch_bounds__(256) void wtrans_k(const float* __restrict__ wq,
                                                const float* __restrict__ wk,
                                                const float* __restrict__ wv,
                                                unsigned short* __restrict__ wt) {
  __shared__ unsigned short lds[64][65];
  const int m  = blockIdx.x >> 4;
  const int c0 = (blockIdx.x & 15) * 64;
  const float* w = (m == 0) ? wq : (m == 1) ? wk : wv;
  const int nl = threadIdx.x & 63, gr = threadIdx.x >> 6;
#pragma unroll
  for (int i = 0; i < 16; ++i) {
    int cl = gr * 16 + i;
    lds[cl][nl] = f2bf(w[(size_t)(c0 + cl) * HDIM + nl]);
  }
  __syncthreads();
#pragma unroll
  for (int i = 0; i < 16; ++i) {
    int n = gr * 16 + i;
    wt[(size_t)m * 65536 + n * CIN + c0 + nl] = lds[nl][n];
  }
}

// ---------------- Kernel 1: QKV projection, LDS-staged GEMM (unchanged) -----
__global__ __launch_bounds__(512) void qkv_proj_k(const float* __restrict__ x,
                                                  const unsigned short* __restrict__ wt,
                                                  unsigned short* __restrict__ q,
                                                  unsigned short* __restrict__ k,
                                                  unsigned short* __restrict__ vt) {
  __shared__ __align__(16) unsigned char ldsb[28672];   // x @0, wt @4096
  const int tid  = threadIdx.x;
  const int lane = tid & 63;
  const int w    = tid >> 6;
  const int lr   = lane & 15, lg = lane >> 4;
  const int wm   = w & 1, wn = w >> 1;
  const int row0 = blockIdx.x * 32;

  const int trow  = tid >> 4;
  const int tcol4 = (tid & 15) * 4;
  const float* xg = x + (size_t)(row0 + trow) * CIN + tcol4;
  const int xoff  = trow * 128 + (((tcol4 >> 3) ^ (trow & 7)) << 4) + ((tcol4 & 4) << 1);

  const int wrow_ = tid >> 3;
  const int wg8   = tid & 7;
  const unsigned short* wg[3];
  int woff[3];
#pragma unroll
  for (int c = 0; c < 3; ++c) {
    int wrow = c * 64 + wrow_;
    wg[c]   = wt + (size_t)wrow * CIN + wg8 * 8;
    woff[c] = 4096 + wrow * 128 + ((wg8 ^ (wrow & 7)) << 4);
  }

  f32x4 acc[3];
#pragma unroll
  for (int i = 0; i < 3; ++i) acc[i] = (f32x4){0.f, 0.f, 0.f, 0.f};

  const int arow_off = (wm * 16 + lr) * 128;
  const int brow0    = wn * 48 + lr;

#pragma unroll 1
  for (int t = 0; t < 16; ++t) {
    const int k0 = t * 64;
    f32x4 xv = *(const f32x4*)(xg + k0);
    bf16x8 w0 = *(const bf16x8*)(wg[0] + k0);
    bf16x8 w1 = *(const bf16x8*)(wg[1] + k0);
    bf16x8 w2 = *(const bf16x8*)(wg[2] + k0);
    __syncthreads();
    *(u16x4*)(void*)(ldsb + xoff)    = pack4(xv);
    *(bf16x8*)(void*)(ldsb + woff[0]) = w0;
    *(bf16x8*)(void*)(ldsb + woff[1]) = w1;
    *(bf16x8*)(void*)(ldsb + woff[2]) = w2;
    __syncthreads();
#pragma unroll
    for (int kk = 0; kk < 2; ++kk) {
      const int swz = (((kk << 2) | lg) ^ (lr & 7)) << 4;
      bf16x8 af = *(const bf16x8*)(void*)(ldsb + arow_off + swz);
#pragma unroll
      for (int f = 0; f < 3; ++f) {
        bf16x8 bf_ = *(const bf16x8*)(void*)(ldsb + 4096 + (brow0 + f * 16) * 128 + swz);
        acc[f] = __builtin_amdgcn_mfma_f32_16x16x32_bf16(af, bf_, acc[f], 0, 0, 0);
      }
    }
  }

#pragma unroll
  for (int f = 0; f < 3; ++f) {
    const int gc  = wn * 48 + f * 16;
    const int mat = gc >> 6;
    const int hd  = (gc & 63) + lr;
#pragma unroll
    for (int j = 0; j < 4; ++j) {
      int grow = row0 + wm * 16 + lg * 4 + j;
      float v = acc[f][j];
      if (mat == 0) {
        q[(size_t)grow * HDIM + hd] = f2bf(v * 0.03125f);   // fold 1/sqrt(C)
      } else if (mat == 1) {
        k[(size_t)grow * HDIM + hd] = f2bf(v);
      } else {
        int b = grow >> 11, tp = grow & 2047;
        vt[((size_t)b * HDIM + hd) * SEQ + tp] = f2bf(v);
      }
    }
  }
}

// ---------------- Kernel 2: flash attention, LDS-shared K/V tiles -----------
// Block = 512 thr / 8 waves = 128 q-rows x 1 segment of 128 keys (2 KV tiles).
// Unit (b, q-block i, seg<i+1): 1088 blocks, perfectly uniform (2 tiles each).
// K,V reg-staged once into XOR-swizzled LDS, shared by all 8 waves (8x less
// global traffic; one latency exposure per block).
__global__ __launch_bounds__(512) void attn_k(const unsigned short* __restrict__ q,
                                              const unsigned short* __restrict__ k,
                                              const unsigned short* __restrict__ vt,
                                              float* __restrict__ opart,
                                              float* __restrict__ m_l) {
  __shared__ __align__(16) unsigned char kv_lds[4][8192];   // K0,V0,K1,V1 swz
  __shared__ __align__(16) unsigned short plds[8][16][72];  // per-wave P
  const int tid  = threadIdx.x;
  const int lane = tid & 63;
  const int w    = tid >> 6;
  const int lr = lane & 15, lg = lane >> 4, lr7 = lane & 7;

  const int blk = blockIdx.x;
  const int b   = blk / UPB;
  const int u   = blk - b * UPB;
  int i = 0;
#pragma unroll
  for (int j = 1; j <= 15; ++j) if (((j * (j + 1)) >> 1) <= u) i = j;
  const int seg  = u - ((i * (i + 1)) >> 1);
  const int r0   = i * 128 + w * 16;        // wave's first q-row
  const int kvb  = seg * 128;               // segment's first key
  const int p    = blk;                     // partial slot

  const unsigned short* qb_ = q  + (size_t)b * SEQ * HDIM;
  const unsigned short* kb_ = k  + (size_t)b * SEQ * HDIM;
  const unsigned short* vb_ = vt + (size_t)b * HDIM * SEQ;

  // ---- stage 2 K tiles + 2 V tiles (32 KB), XOR-swizzled, one sync --------
  const int srow = tid >> 3;                // 0..63
  const int sg   = tid & 7;                 // 16B granule
  const unsigned short* ks0 = kb_ + (size_t)(kvb + srow) * HDIM + sg * 8;
  const unsigned short* vs0 = vb_ + (size_t)srow * SEQ + kvb + sg * 8;
  bf16x8 kv0 = *(const bf16x8*)(ks0);
  bf16x8 vv0 = *(const bf16x8*)(vs0);
  bf16x8 kv1 = *(const bf16x8*)(ks0 + 64 * HDIM);
  bf16x8 vv1 = *(const bf16x8*)(vs0 + 64);
  bf16x8 qf0 = *(const bf16x8*)(qb_ + (size_t)(r0 + lr) * HDIM + lg * 8);
  bf16x8 qf1 = *(const bf16x8*)(qb_ + (size_t)(r0 + lr) * HDIM + 32 + lg * 8);
  const int soff = srow * 128 + ((sg ^ (srow & 7)) << 4);
  *(bf16x8*)(kv_lds[0] + soff) = kv0;
  *(bf16x8*)(kv_lds[1] + soff) = vv0;
  *(bf16x8*)(kv_lds[2] + soff) = kv1;
  *(bf16x8*)(kv_lds[3] + soff) = vv1;
  __syncthreads();

  f32x4 o[4];
#pragma unroll
  for (int n = 0; n < 4; ++n) o[n] = (f32x4){0.f, 0.f, 0.f, 0.f};
  float m_run = -INFINITY, l_run = 0.f;
  const int   qrow = r0 + lr;
  const float LOG2E = 1.44269504f;
  unsigned short (*pw)[72] = plds[w];

#pragma unroll 1
  for (int tt = 0; tt < 2; ++tt) {
    const int kv = kvb + tt * 64;
    if (kv > r0 + 15) continue;             // wave-uniform: fully masked tile
    const unsigned char* Kt = kv_lds[tt * 2];
    const unsigned char* Vt = kv_lds[tt * 2 + 1];

    f32x4 sv[4];
#pragma unroll
    for (int f = 0; f < 4; ++f) {
      const int base = (f * 16 + lr) * 128;
      bf16x8 ka0 = *(const bf16x8*)(Kt + base + ((lg ^ lr7) << 4));
      bf16x8 ka1 = *(const bf16x8*)(Kt + base + (((4 + lg) ^ lr7) << 4));
      sv[f] = (f32x4){0.f, 0.f, 0.f, 0.f};
      sv[f] = __builtin_amdgcn_mfma_f32_16x16x32_bf16(ka0, qf0, sv[f], 0, 0, 0);
      sv[f] = __builtin_amdgcn_mfma_f32_16x16x32_bf16(ka1, qf1, sv[f], 0, 0, 0);
    }
    if (kv + 63 > r0) {                     // tile touches diagonal
#pragma unroll
      for (int f = 0; f < 4; ++f)
#pragma unroll
        for (int j = 0; j < 4; ++j)
          if (kv + f * 16 + lg * 4 + j > qrow) sv[f][j] = -INFINITY;
    }
    float tm = -INFINITY;
#pragma unroll
    for (int f = 0; f < 4; ++f)
#pragma unroll
      for (int j = 0; j < 4; ++j) tm = fmaxf(tm, sv[f][j]);
    tm = fmaxf(tm, __shfl_xor(tm, 16, 64));
    tm = fmaxf(tm, __shfl_xor(tm, 32, 64));
    float m_new = fmaxf(m_run, tm);
    float alpha = (m_run == -INFINITY) ? 0.f : exp2f((m_run - m_new) * LOG2E);
    float mc    = (m_new == -INFINITY) ? 0.f : m_new * LOG2E;
    float ps = 0.f;
#pragma unroll
    for (int f = 0; f < 4; ++f) {
      float p0 = exp2f(sv[f][0] * LOG2E - mc);
      float p1 = exp2f(sv[f][1] * LOG2E - mc);
      float p2 = exp2f(sv[f][2] * LOG2E - mc);
      float p3 = exp2f(sv[f][3] * LOG2E - mc);
      ps += (p0 + p1) + (p2 + p3);
      unsigned int lo32 = (unsigned int)f2bf(p0) | ((unsigned int)f2bf(p1) << 16);
      unsigned int hi32 = (unsigned int)f2bf(p2) | ((unsigned int)f2bf(p3) << 16);
      uint2 pk; pk.x = lo32; pk.y = hi32;
      *(uint2*)(&pw[lr][f * 16 + lg * 4]) = pk;   // ds_write_b64
    }
    ps += __shfl_xor(ps, 16, 64);
    ps += __shfl_xor(ps, 32, 64);
    l_run = l_run * alpha + ps;
    m_run = m_new;
#pragma unroll
    for (int j = 0; j < 4; ++j) {
      float aj = __shfl(alpha, lg * 4 + j, 64);
      o[0][j] *= aj; o[1][j] *= aj; o[2][j] *= aj; o[3][j] *= aj;
    }
    // in-wave DS ordering: drain this wave's DS writes, then read P
    asm volatile("s_waitcnt lgkmcnt(0)" ::: "memory");
    __builtin_amdgcn_sched_barrier(0);
#pragma unroll
    for (int kk = 0; kk < 2; ++kk) {
      bf16x8 pf = *(const bf16x8*)(&pw[lr][kk * 32 + lg * 8]);
#pragma unroll
      for (int n = 0; n < 4; ++n) {
        bf16x8 vf = *(const bf16x8*)(Vt + (n * 16 + lr) * 128 + (((kk * 4 + lg) ^ lr7) << 4));
        o[n] = __builtin_amdgcn_mfma_f32_16x16x32_bf16(pf, vf, o[n], 0, 0, 0);
      }
    }
  }

  if (lane < 16) {
    m_l[p * 256 + w * 16 + lane]       = m_run;
    m_l[p * 256 + 128 + w * 16 + lane] = l_run;
  }
#pragma unroll
  for (int j = 0; j < 4; ++j) {
    int rloc = w * 16 + lg * 4 + j;
#pragma unroll
    for (int n = 0; n < 4; ++n)
      opart[(size_t)p * 8192 + rloc * 64 + n * 16 + lr] = o[n][j];
  }
}

// ---------------- Kernel 3: combine variable-split partials -----------------
__global__ __launch_bounds__(256) void combine_k(const float* __restrict__ opart,
                                                 const float* __restrict__ m_l,
                                                 float* __restrict__ out) {
  const float LOG2E = 1.44269504f;
  int idx = blockIdx.x * 256 + threadIdx.x;
  int col = idx & 63;
  int row = idx >> 6;
  int b = row >> 11, t = row & 2047;
  int i = t >> 7, r = t & 127;              // q-block, row within block
  int S = i + 1;
  int pb = b * UPB + ((i * (i + 1)) >> 1);  // first slot for this q-block
  float M = -INFINITY;
  for (int s = 0; s < S; ++s) M = fmaxf(M, m_l[(pb + s) * 256 + r]);
  float l = 0.f, o = 0.f;
  for (int s = 0; s < S; ++s) {
    float ms = m_l[(pb + s) * 256 + r];
    float w  = exp2f((ms - M) * LOG2E);
    l += m_l[(pb + s) * 256 + 128 + r] * w;
    o += opart[(size_t)(pb + s) * 8192 + r * 64 + col] * w;
  }
  out[(size_t)row * HDIM + col] = o / l;
}

// ---------------- launch ----------------------------------------------------
extern "C" void kernel_launch(void* const* d_in, const int* in_sizes, int n_in,
                              void* d_out, int out_size, void* d_ws, size_t ws_size,
                              hipStream_t stream) {
  const float* x  = (const float*)d_in[0];
  const float* wq = (const float*)d_in[1];
  const float* wk = (const float*)d_in[2];
  const float* wv = (const float*)d_in[3];
  float* outp = (float*)d_out;

  float* m_l   = (float*)d_ws;                          // [NPB][256]
  float* opart = m_l + (size_t)NPB * 256;               // [NPB][128][64]
  unsigned short* qbuf = (unsigned short*)(opart + (size_t)NPB * 8192);
  unsigned short* kbuf = qbuf + (size_t)NROW * HDIM;
  unsigned short* vbuf = kbuf + (size_t)NROW * HDIM;    // [B][64][T]
  unsigned short* wt   = vbuf + (size_t)NROW * HDIM;    // [3][64][1024]

  hipLaunchKernelGGL(wtrans_k, dim3(48), dim3(256), 0, stream, wq, wk, wv, wt);
  hipLaunchKernelGGL(qkv_proj_k, dim3(NROW / 32), dim3(512), 0, stream, x, wt, qbuf, kbuf, vbuf);
  hipLaunchKernelGGL(attn_k, dim3(NPB), dim3(512), 0, stream, qbuf, kbuf, vbuf, opart, m_l);
  hipLaunchKernelGGL(combine_k, dim3(NROW * HDIM / 256), dim3(256), 0, stream, opart, m_l, outp);
}

// Round 10
// 145.152 us; speedup vs baseline: 1.1454x; 1.0428x over previous
//
#include <hip/hip_runtime.h>

// Dtype contract: device buffers FP32 (reference dtypes); internal bf16 MFMA,
// fp32 accumulate. Tolerance is bf16-grade (2% of absmax).
// dur_us model: Σ(kernels) + ~65-68 us fixed harness resets.
// R8/R9 unified lesson: hipcc's VGPR target follows achievable occupancy
// (LDS-bound). Small-LDS kernels get squeezed to 60-64 VGPR and every load
// sinks to its use (1 VMEM in flight). Big-LDS kernels get a 128-256 VGPR
// budget and the scheduler hoists prefetch loads itself. So: stage in bulk,
// double-buffer, let LDS size set the register budget.

#define BATCH 8
#define SEQ   2048
#define CIN   1024
#define HDIM  64
#define NROW  (BATCH * SEQ)      // 16384
#define UPB   136                // attn units per batch: sum_{i=0..15} (i+1)
#define NPB   (BATCH * UPB)      // 1088 attn blocks / partial slots

typedef __attribute__((ext_vector_type(8))) short bf16x8;
typedef __attribute__((ext_vector_type(4))) short u16x4;
typedef __attribute__((ext_vector_type(4))) float f32x4;

__device__ __forceinline__ unsigned short f2bf(float f) {
  unsigned int u = __builtin_bit_cast(unsigned int, f);
  u += 0x7fffu + ((u >> 16) & 1u);          // RNE
  return (unsigned short)(u >> 16);
}
__device__ __forceinline__ float bf2f(unsigned short h) {
  return __builtin_bit_cast(float, (unsigned int)h << 16);
}
__device__ __forceinline__ bf16x8 pack8(f32x4 a, f32x4 b) {
  bf16x8 r;
  r[0] = (short)f2bf(a[0]); r[1] = (short)f2bf(a[1]);
  r[2] = (short)f2bf(a[2]); r[3] = (short)f2bf(a[3]);
  r[4] = (short)f2bf(b[0]); r[5] = (short)f2bf(b[1]);
  r[6] = (short)f2bf(b[2]); r[7] = (short)f2bf(b[3]);
  return r;
}

// ---------------- Kernel 0: W [C][HD] fp32 -> Wt [HD][C] bf16 (LDS tiles) ---
__global__ __launch_bounds__(256) void wtrans_k(const float* __restrict__ wq,
                                                const float* __restrict__ wk,
                                                const float* __restrict__ wv,
                                                unsigned short* __restrict__ wt) {
  __shared__ unsigned short lds[64][65];
  const int m  = blockIdx.x >> 4;
  const int c0 = (blockIdx.x & 15) * 64;
  const float* w = (m == 0) ? wq : (m == 1) ? wk : wv;
  const int nl = threadIdx.x & 63, gr = threadIdx.x >> 6;
#pragma unroll
  for (int i = 0; i < 16; ++i) {
    int cl = gr * 16 + i;
    lds[cl][nl] = f2bf(w[(size_t)(c0 + cl) * HDIM + nl]);
  }
  __syncthreads();
#pragma unroll
  for (int i = 0; i < 16; ++i) {
    int n = gr * 16 + i;
    wt[(size_t)m * 65536 + n * CIN + c0 + nl] = lds[nl][n];
  }
}

// ---------------- Kernel 1: QKV projection, 2-phase double-buffered GEMM ----
// 256 blocks x 512 thr (8 waves, 4 wm x 2 wn). Block: 64 rows x 192 cols,
// 16 K-steps of 64. LDS 2 x (x-bf16 8KB + wt 24.6KB) = 65.5KB -> VGPR budget
// ~128 (2 blocks/CU by LDS). Per step: write staged regs -> ONE barrier ->
// issue next-step loads -> compute (12 MFMA/wave). Loads land under compute.
#define QXB  8192
#define QWB  24576
#define QBUF 32768
__global__ __launch_bounds__(512) void qkv_proj_k(const float* __restrict__ x,
                                                  const unsigned short* __restrict__ wt,
                                                  unsigned short* __restrict__ q,
                                                  unsigned short* __restrict__ k,
                                                  unsigned short* __restrict__ vt) {
  __shared__ __align__(16) unsigned char ldsb[2 * QBUF];
  const int tid  = threadIdx.x;
  const int lane = tid & 63;
  const int w    = tid >> 6;
  const int lr   = lane & 15, lg = lane >> 4, lr7 = lane & 7;
  const int wm   = w & 3, wn = w >> 2;
  const int row0 = blockIdx.x * 64;

  // staging maps: thread -> (row = tid>>3, 16B granule g = tid&7)
  const int srow = tid >> 3;
  const int sg   = tid & 7;
  const float*          xg  = x  + (size_t)(row0 + srow) * CIN + sg * 8;
  const unsigned short* wgp = wt + (size_t)srow * CIN + sg * 8;   // + 64*CIN, +128*CIN
  const int soff = srow * 128 + ((sg ^ (srow & 7)) << 4);         // XOR-swizzled

  f32x4 acc[6];
#pragma unroll
  for (int i = 0; i < 6; ++i) acc[i] = (f32x4){0.f, 0.f, 0.f, 0.f};

  // prologue: load tile 0 into regs
  f32x4  xa = *(const f32x4*)(xg);
  f32x4  xb = *(const f32x4*)(xg + 4);
  bf16x8 w0 = *(const bf16x8*)(wgp);
  bf16x8 w1 = *(const bf16x8*)(wgp + 64 * CIN);
  bf16x8 w2 = *(const bf16x8*)(wgp + 128 * CIN);

#pragma unroll 2
  for (int t = 0; t < 16; ++t) {
    unsigned char* buf = ldsb + (t & 1) * QBUF;
    // (1) write tile t from regs (convert x to bf16 here)
    *(bf16x8*)(buf + soff)               = pack8(xa, xb);
    *(bf16x8*)(buf + QXB + soff)         = w0;
    *(bf16x8*)(buf + QXB + soff + 8192)  = w1;
    *(bf16x8*)(buf + QXB + soff + 16384) = w2;
    __syncthreads();                       // single barrier per step (dbuf-safe)
    // (2) issue tile t+1 loads — a full compute phase to land
    if (t < 15) {
      const int k0 = (t + 1) * 64;
      xa = *(const f32x4*)(xg + k0);
      xb = *(const f32x4*)(xg + k0 + 4);
      w0 = *(const bf16x8*)(wgp + k0);
      w1 = *(const bf16x8*)(wgp + 64 * CIN + k0);
      w2 = *(const bf16x8*)(wgp + 128 * CIN + k0);
    }
    // (3) compute tile t
#pragma unroll
    for (int kk = 0; kk < 2; ++kk) {
      const int swz = (((kk << 2) | lg) ^ lr7) << 4;
      bf16x8 af = *(const bf16x8*)(void*)(buf + (wm * 16 + lr) * 128 + swz);
#pragma unroll
      for (int f = 0; f < 6; ++f) {
        bf16x8 bf_ = *(const bf16x8*)(void*)(buf + QXB + (wn * 96 + f * 16 + lr) * 128 + swz);
        acc[f] = __builtin_amdgcn_mfma_f32_16x16x32_bf16(af, bf_, acc[f], 0, 0, 0);
      }
    }
  }

  // C/D: row = lg*4+j, col = lr  [m89/m91]
#pragma unroll
  for (int f = 0; f < 6; ++f) {
    const int gc  = wn * 96 + f * 16;
    const int mat = gc >> 6;
    const int hd  = (gc & 63) + lr;
#pragma unroll
    for (int j = 0; j < 4; ++j) {
      int grow = row0 + wm * 16 + lg * 4 + j;
      float v = acc[f][j];
      if (mat == 0) {
        q[(size_t)grow * HDIM + hd] = f2bf(v * 0.03125f);   // fold 1/sqrt(C)
      } else if (mat == 1) {
        k[(size_t)grow * HDIM + hd] = f2bf(v);
      } else {
        int b = grow >> 11, tp = grow & 2047;
        vt[((size_t)b * HDIM + hd) * SEQ + tp] = f2bf(v);
      }
    }
  }
}

// ---------------- Kernel 2: flash attention, LDS-shared K/V tiles -----------
// (unchanged from round 9: ~23 us)
__global__ __launch_bounds__(512) void attn_k(const unsigned short* __restrict__ q,
                                              const unsigned short* __restrict__ k,
                                              const unsigned short* __restrict__ vt,
                                              float* __restrict__ opart,
                                              float* __restrict__ m_l) {
  __shared__ __align__(16) unsigned char kv_lds[4][8192];   // K0,V0,K1,V1 swz
  __shared__ __align__(16) unsigned short plds[8][16][72];  // per-wave P
  const int tid  = threadIdx.x;
  const int lane = tid & 63;
  const int w    = tid >> 6;
  const int lr = lane & 15, lg = lane >> 4, lr7 = lane & 7;

  const int blk = blockIdx.x;
  const int b   = blk / UPB;
  const int u   = blk - b * UPB;
  int i = 0;
#pragma unroll
  for (int j = 1; j <= 15; ++j) if (((j * (j + 1)) >> 1) <= u) i = j;
  const int seg  = u - ((i * (i + 1)) >> 1);
  const int r0   = i * 128 + w * 16;        // wave's first q-row
  const int kvb  = seg * 128;               // segment's first key
  const int p    = blk;                     // partial slot

  const unsigned short* qb_ = q  + (size_t)b * SEQ * HDIM;
  const unsigned short* kb_ = k  + (size_t)b * SEQ * HDIM;
  const unsigned short* vb_ = vt + (size_t)b * HDIM * SEQ;

  const int srow = tid >> 3;                // 0..63
  const int sg   = tid & 7;                 // 16B granule
  const unsigned short* ks0 = kb_ + (size_t)(kvb + srow) * HDIM + sg * 8;
  const unsigned short* vs0 = vb_ + (size_t)srow * SEQ + kvb + sg * 8;
  bf16x8 kv0 = *(const bf16x8*)(ks0);
  bf16x8 vv0 = *(const bf16x8*)(vs0);
  bf16x8 kv1 = *(const bf16x8*)(ks0 + 64 * HDIM);
  bf16x8 vv1 = *(const bf16x8*)(vs0 + 64);
  bf16x8 qf0 = *(const bf16x8*)(qb_ + (size_t)(r0 + lr) * HDIM + lg * 8);
  bf16x8 qf1 = *(const bf16x8*)(qb_ + (size_t)(r0 + lr) * HDIM + 32 + lg * 8);
  const int soff = srow * 128 + ((sg ^ (srow & 7)) << 4);
  *(bf16x8*)(kv_lds[0] + soff) = kv0;
  *(bf16x8*)(kv_lds[1] + soff) = vv0;
  *(bf16x8*)(kv_lds[2] + soff) = kv1;
  *(bf16x8*)(kv_lds[3] + soff) = vv1;
  __syncthreads();

  f32x4 o[4];
#pragma unroll
  for (int n = 0; n < 4; ++n) o[n] = (f32x4){0.f, 0.f, 0.f, 0.f};
  float m_run = -INFINITY, l_run = 0.f;
  const int   qrow = r0 + lr;
  const float LOG2E = 1.44269504f;
  unsigned short (*pw)[72] = plds[w];

#pragma unroll 1
  for (int tt = 0; tt < 2; ++tt) {
    const int kv = kvb + tt * 64;
    if (kv > r0 + 15) continue;             // wave-uniform: fully masked tile
    const unsigned char* Kt = kv_lds[tt * 2];
    const unsigned char* Vt = kv_lds[tt * 2 + 1];

    f32x4 sv[4];
#pragma unroll
    for (int f = 0; f < 4; ++f) {
      const int base = (f * 16 + lr) * 128;
      bf16x8 ka0 = *(const bf16x8*)(Kt + base + ((lg ^ lr7) << 4));
      bf16x8 ka1 = *(const bf16x8*)(Kt + base + (((4 + lg) ^ lr7) << 4));
      sv[f] = (f32x4){0.f, 0.f, 0.f, 0.f};
      sv[f] = __builtin_amdgcn_mfma_f32_16x16x32_bf16(ka0, qf0, sv[f], 0, 0, 0);
      sv[f] = __builtin_amdgcn_mfma_f32_16x16x32_bf16(ka1, qf1, sv[f], 0, 0, 0);
    }
    if (kv + 63 > r0) {                     // tile touches diagonal
#pragma unroll
      for (int f = 0; f < 4; ++f)
#pragma unroll
        for (int j = 0; j < 4; ++j)
          if (kv + f * 16 + lg * 4 + j > qrow) sv[f][j] = -INFINITY;
    }
    float tm = -INFINITY;
#pragma unroll
    for (int f = 0; f < 4; ++f)
#pragma unroll
      for (int j = 0; j < 4; ++j) tm = fmaxf(tm, sv[f][j]);
    tm = fmaxf(tm, __shfl_xor(tm, 16, 64));
    tm = fmaxf(tm, __shfl_xor(tm, 32, 64));
    float m_new = fmaxf(m_run, tm);
    float alpha = (m_run == -INFINITY) ? 0.f : exp2f((m_run - m_new) * LOG2E);
    float mc    = (m_new == -INFINITY) ? 0.f : m_new * LOG2E;
    float ps = 0.f;
#pragma unroll
    for (int f = 0; f < 4; ++f) {
      float p0 = exp2f(sv[f][0] * LOG2E - mc);
      float p1 = exp2f(sv[f][1] * LOG2E - mc);
      float p2 = exp2f(sv[f][2] * LOG2E - mc);
      float p3 = exp2f(sv[f][3] * LOG2E - mc);
      ps += (p0 + p1) + (p2 + p3);
      unsigned int lo32 = (unsigned int)f2bf(p0) | ((unsigned int)f2bf(p1) << 16);
      unsigned int hi32 = (unsigned int)f2bf(p2) | ((unsigned int)f2bf(p3) << 16);
      uint2 pk; pk.x = lo32; pk.y = hi32;
      *(uint2*)(&pw[lr][f * 16 + lg * 4]) = pk;   // ds_write_b64
    }
    ps += __shfl_xor(ps, 16, 64);
    ps += __shfl_xor(ps, 32, 64);
    l_run = l_run * alpha + ps;
    m_run = m_new;
#pragma unroll
    for (int j = 0; j < 4; ++j) {
      float aj = __shfl(alpha, lg * 4 + j, 64);
      o[0][j] *= aj; o[1][j] *= aj; o[2][j] *= aj; o[3][j] *= aj;
    }
    asm volatile("s_waitcnt lgkmcnt(0)" ::: "memory");
    __builtin_amdgcn_sched_barrier(0);
#pragma unroll
    for (int kk = 0; kk < 2; ++kk) {
      bf16x8 pf = *(const bf16x8*)(&pw[lr][kk * 32 + lg * 8]);
#pragma unroll
      for (int n = 0; n < 4; ++n) {
        bf16x8 vf = *(const bf16x8*)(Vt + (n * 16 + lr) * 128 + (((kk * 4 + lg) ^ lr7) << 4));
        o[n] = __builtin_amdgcn_mfma_f32_16x16x32_bf16(pf, vf, o[n], 0, 0, 0);
      }
    }
  }

  if (lane < 16) {
    m_l[p * 256 + w * 16 + lane]       = m_run;
    m_l[p * 256 + 128 + w * 16 + lane] = l_run;
  }
#pragma unroll
  for (int j = 0; j < 4; ++j) {
    int rloc = w * 16 + lg * 4 + j;
#pragma unroll
    for (int n = 0; n < 4; ++n)
      opart[(size_t)p * 8192 + rloc * 64 + n * 16 + lr] = o[n][j];
  }
}

// ---------------- Kernel 3: combine variable-split partials -----------------
__global__ __launch_bounds__(256) void combine_k(const float* __restrict__ opart,
                                                 const float* __restrict__ m_l,
                                                 float* __restrict__ out) {
  const float LOG2E = 1.44269504f;
  int idx = blockIdx.x * 256 + threadIdx.x;
  int col = idx & 63;
  int row = idx >> 6;
  int b = row >> 11, t = row & 2047;
  int i = t >> 7, r = t & 127;              // q-block, row within block
  int S = i + 1;
  int pb = b * UPB + ((i * (i + 1)) >> 1);  // first slot for this q-block
  float M = -INFINITY;
  for (int s = 0; s < S; ++s) M = fmaxf(M, m_l[(pb + s) * 256 + r]);
  float l = 0.f, o = 0.f;
  for (int s = 0; s < S; ++s) {
    float ms = m_l[(pb + s) * 256 + r];
    float w  = exp2f((ms - M) * LOG2E);
    l += m_l[(pb + s) * 256 + 128 + r] * w;
    o += opart[(size_t)(pb + s) * 8192 + r * 64 + col] * w;
  }
  out[(size_t)row * HDIM + col] = o / l;
}

// ---------------- launch ----------------------------------------------------
extern "C" void kernel_launch(void* const* d_in, const int* in_sizes, int n_in,
                              void* d_out, int out_size, void* d_ws, size_t ws_size,
                              hipStream_t stream) {
  const float* x  = (const float*)d_in[0];
  const float* wq = (const float*)d_in[1];
  const float* wk = (const float*)d_in[2];
  const float* wv = (const float*)d_in[3];
  float* outp = (float*)d_out;

  float* m_l   = (float*)d_ws;                          // [NPB][256]
  float* opart = m_l + (size_t)NPB * 256;               // [NPB][128][64]
  unsigned short* qbuf = (unsigned short*)(opart + (size_t)NPB * 8192);
  unsigned short* kbuf = qbuf + (size_t)NROW * HDIM;
  unsigned short* vbuf = kbuf + (size_t)NROW * HDIM;    // [B][64][T]
  unsigned short* wt   = vbuf + (size_t)NROW * HDIM;    // [3][64][1024]

  hipLaunchKernelGGL(wtrans_k, dim3(48), dim3(256), 0, stream, wq, wk, wv, wt);
  hipLaunchKernelGGL(qkv_proj_k, dim3(NROW / 64), dim3(512), 0, stream, x, wt, qbuf, kbuf, vbuf);
  hipLaunchKernelGGL(attn_k, dim3(NPB), dim3(512), 0, stream, qbuf, kbuf, vbuf, opart, m_l);
  hipLaunchKernelGGL(combine_k, dim3(NROW * HDIM / 256), dim3(256), 0, stream, opart, m_l, outp);
}